// Round 5
// baseline (56.160 us; speedup 1.0000x reference)
//
#include <hip/hip_runtime.h>

// EulerToAffine: per row, angles (ax,ay,az) + translation t -> 3x4 [R|t], R = Rx*Ry*Rz.
//   R00 = cy*cz          R01 = -cy*sz          R02 = sy
//   R10 = cx*sz+sx*sy*cz R11 = cx*cz-sx*sy*sz  R12 = -sx*cy
//   R20 = sx*sz-cx*sy*cz R21 = sx*cz+cx*sy*sz  R22 = cx*cy
// Output row: R00 R01 R02 t0 | R10 R11 R12 t1 | R20 R21 R22 t2
//
// Ladder: R1 direct strided = 102us (partial-line stores -> RFO).
// R2 LDS-staged stores = 54.0us. R3 occupancy/barrier tweaks = neutral
// (54.6us). R4: nontemporal ld/st (touch-once streams; avoid L2/L3
// retention churn). R4 fix: __builtin_nontemporal_* needs a clang ext
// vector type, not HIP's float4 class.

typedef float f32x4 __attribute__((ext_vector_type(4)));

__device__ __forceinline__ void euler_row(float ax, float ay, float az,
                                          float tx, float ty, float tz,
                                          f32x4& o0, f32x4& o1, f32x4& o2) {
    float sx, cx, sy, cy, sz, cz;
    __sincosf(ax, &sx, &cx);
    __sincosf(ay, &sy, &cy);
    __sincosf(az, &sz, &cz);

    float sycz = sy * cz;
    float sysz = sy * sz;

    o0.x = cy * cz;
    o0.y = -cy * sz;
    o0.z = sy;
    o0.w = tx;

    o1.x = fmaf(sx, sycz, cx * sz);
    o1.y = fmaf(-sx, sysz, cx * cz);
    o1.z = -sx * cy;
    o1.w = ty;

    o2.x = fmaf(-cx, sycz, sx * sz);
    o2.y = fmaf(cx, sysz, sx * cz);
    o2.z = cx * cy;
    o2.w = tz;
}

// Chunk = 512 rows. Each thread: 3 direct nt f32x4 loads (rows 2t,2t+1),
// compute, 6 f32x4 -> s_out, then 6 lane-contiguous nt f32x4 stores.
__global__ __launch_bounds__(256) void EulerToAffine_74208444940704_kernel(
        const f32x4* __restrict__ in4, f32x4* __restrict__ out4, int nchunks) {
    __shared__ f32x4 s_out[1536];   // 24 KB
    const int t = threadIdx.x;

    for (int c = blockIdx.x; c < nchunks; c += gridDim.x) {
        const f32x4* ip = in4 + (size_t)c * 768 + (size_t)t * 3;
        f32x4 a  = __builtin_nontemporal_load(ip);
        f32x4 b  = __builtin_nontemporal_load(ip + 1);
        f32x4 cc = __builtin_nontemporal_load(ip + 2);

        f32x4 o0, o1, o2, o3, o4, o5;
        euler_row(a.x, a.y, a.z, a.w, b.x, b.y, o0, o1, o2);
        euler_row(b.z, b.w, cc.x, cc.y, cc.z, cc.w, o3, o4, o5);

        __syncthreads();   // WAR: prior chunk's s_out reads done before overwrite
        f32x4* op = s_out + t * 6;
        op[0] = o0; op[1] = o1; op[2] = o2;
        op[3] = o3; op[4] = o4; op[5] = o5;
        __syncthreads();   // writes visible before coalesced read-out

        f32x4* ob = out4 + (size_t)c * 1536;
        #pragma unroll
        for (int j = 0; j < 6; ++j)
            __builtin_nontemporal_store(s_out[j * 256 + t], ob + j * 256 + t);
    }
}

// Tail (not hit at N=4194304 = 8192 full chunks).
__global__ __launch_bounds__(256) void EulerToAffine_tail_kernel(
        const float* __restrict__ in, float* __restrict__ out,
        int row0, int nrows) {
    int r = row0 + blockIdx.x * blockDim.x + threadIdx.x;
    if (r >= nrows) return;
    const float* ip = in + (size_t)r * 6;
    f32x4 o0, o1, o2;
    euler_row(ip[0], ip[1], ip[2], ip[3], ip[4], ip[5], o0, o1, o2);
    float* op = out + (size_t)r * 12;
    op[0] = o0.x; op[1] = o0.y; op[2]  = o0.z; op[3]  = o0.w;
    op[4] = o1.x; op[5] = o1.y; op[6]  = o1.z; op[7]  = o1.w;
    op[8] = o2.x; op[9] = o2.y; op[10] = o2.z; op[11] = o2.w;
}

extern "C" void kernel_launch(void* const* d_in, const int* in_sizes, int n_in,
                              void* d_out, int out_size, void* d_ws, size_t ws_size,
                              hipStream_t stream) {
    const float* in = (const float*)d_in[0];
    float* out = (float*)d_out;
    int nrows = in_sizes[0] / 6;          // 4194304
    int nchunks = nrows / 512;            // 8192 full chunks

    if (nchunks > 0) {
        // One chunk per block: finest backfill granularity, no residency
        // quantization (24KB LDS -> 6 blocks/CU -> 1536 resident).
        EulerToAffine_74208444940704_kernel<<<nchunks, 256, 0, stream>>>(
            (const f32x4*)in, (f32x4*)out, nchunks);
    }
    int done = nchunks * 512;
    int rem = nrows - done;
    if (rem > 0) {
        EulerToAffine_tail_kernel<<<(rem + 255) / 256, 256, 0, stream>>>(
            in, out, done, nrows);
    }
}

// Round 6
// 48.684 us; speedup vs baseline: 1.1536x; 1.1536x over previous
//
#include <hip/hip_runtime.h>

// EulerToAffine: per row, angles (ax,ay,az) + translation t -> 3x4 [R|t], R = Rx*Ry*Rz.
//   R00 = cy*cz          R01 = -cy*sz          R02 = sy
//   R10 = cx*sz+sx*sy*cz R11 = cx*cz-sx*sy*sz  R12 = -sx*cy
//   R20 = sx*sz-cx*sy*cz R21 = sx*cz+cx*sy*sz  R22 = cx*cy
// Output row: R00 R01 R02 t0 | R10 R11 R12 t1 | R20 R21 R22 t2
//
// Ladder: R1 direct strided = 102us (partial-line stores). R2 LDS-staged
// stores = 54.0us. R3 occupancy/barriers = neutral (54.6). R5 nt-both =
// 56.2 (REGRESSION: nt loads broke L1 reuse of the 3x-overlapping strided
// input reads). R6: nt STORES only (touch-once output = 2/3 of traffic),
// normal loads, back to R2's grid=2048.

typedef float f32x4 __attribute__((ext_vector_type(4)));

__device__ __forceinline__ void euler_row(float ax, float ay, float az,
                                          float tx, float ty, float tz,
                                          f32x4& o0, f32x4& o1, f32x4& o2) {
    float sx, cx, sy, cy, sz, cz;
    __sincosf(ax, &sx, &cx);
    __sincosf(ay, &sy, &cy);
    __sincosf(az, &sz, &cz);

    float sycz = sy * cz;
    float sysz = sy * sz;

    o0.x = cy * cz;
    o0.y = -cy * sz;
    o0.z = sy;
    o0.w = tx;

    o1.x = fmaf(sx, sycz, cx * sz);
    o1.y = fmaf(-sx, sysz, cx * cz);
    o1.z = -sx * cy;
    o1.w = ty;

    o2.x = fmaf(-cx, sycz, sx * sz);
    o2.y = fmaf(cx, sysz, sx * cz);
    o2.z = cx * cy;
    o2.w = tz;
}

// Chunk = 512 rows. Each thread: 3 direct (cached) f32x4 loads, compute,
// 6 f32x4 -> s_out, then 6 lane-contiguous NT f32x4 stores.
__global__ __launch_bounds__(256) void EulerToAffine_74208444940704_kernel(
        const f32x4* __restrict__ in4, f32x4* __restrict__ out4, int nchunks) {
    __shared__ f32x4 s_out[1536];   // 24 KB
    const int t = threadIdx.x;

    for (int c = blockIdx.x; c < nchunks; c += gridDim.x) {
        const f32x4* ip = in4 + (size_t)c * 768 + (size_t)t * 3;
        f32x4 a  = ip[0];
        f32x4 b  = ip[1];
        f32x4 cc = ip[2];

        f32x4 o0, o1, o2, o3, o4, o5;
        euler_row(a.x, a.y, a.z, a.w, b.x, b.y, o0, o1, o2);
        euler_row(b.z, b.w, cc.x, cc.y, cc.z, cc.w, o3, o4, o5);

        __syncthreads();   // WAR: prior chunk's s_out reads done before overwrite
        f32x4* op = s_out + t * 6;
        op[0] = o0; op[1] = o1; op[2] = o2;
        op[3] = o3; op[4] = o4; op[5] = o5;
        __syncthreads();   // writes visible before coalesced read-out

        f32x4* ob = out4 + (size_t)c * 1536;
        #pragma unroll
        for (int j = 0; j < 6; ++j)
            __builtin_nontemporal_store(s_out[j * 256 + t], ob + j * 256 + t);
    }
}

// Tail (not hit at N=4194304 = 8192 full chunks).
__global__ __launch_bounds__(256) void EulerToAffine_tail_kernel(
        const float* __restrict__ in, float* __restrict__ out,
        int row0, int nrows) {
    int r = row0 + blockIdx.x * blockDim.x + threadIdx.x;
    if (r >= nrows) return;
    const float* ip = in + (size_t)r * 6;
    f32x4 o0, o1, o2;
    euler_row(ip[0], ip[1], ip[2], ip[3], ip[4], ip[5], o0, o1, o2);
    float* op = out + (size_t)r * 12;
    op[0] = o0.x; op[1] = o0.y; op[2]  = o0.z; op[3]  = o0.w;
    op[4] = o1.x; op[5] = o1.y; op[6]  = o1.z; op[7]  = o1.w;
    op[8] = o2.x; op[9] = o2.y; op[10] = o2.z; op[11] = o2.w;
}

extern "C" void kernel_launch(void* const* d_in, const int* in_sizes, int n_in,
                              void* d_out, int out_size, void* d_ws, size_t ws_size,
                              hipStream_t stream) {
    const float* in = (const float*)d_in[0];
    float* out = (float*)d_out;
    int nrows = in_sizes[0] / 6;          // 4194304
    int nchunks = nrows / 512;            // 8192 full chunks

    if (nchunks > 0) {
        int grid = nchunks < 2048 ? nchunks : 2048;
        EulerToAffine_74208444940704_kernel<<<grid, 256, 0, stream>>>(
            (const f32x4*)in, (f32x4*)out, nchunks);
    }
    int done = nchunks * 512;
    int rem = nrows - done;
    if (rem > 0) {
        EulerToAffine_tail_kernel<<<(rem + 255) / 256, 256, 0, stream>>>(
            in, out, done, nrows);
    }
}